// Round 5
// baseline (58.785 us; speedup 1.0000x reference)
//
#include <hip/hip_runtime.h>
#include <cstdint>
#include <cstddef>

#define BB 2
#define FF 16
#define NPT 128
#define CC 1280
#define MID 128

typedef __attribute__((ext_vector_type(8))) short bf16x8;
typedef __attribute__((ext_vector_type(4))) float f32x4;

__device__ __forceinline__ unsigned short f2bf(float f) {
  unsigned u = __builtin_bit_cast(unsigned, f);
  u += 0x7FFFu + ((u >> 16) & 1u);  // RNE
  return (unsigned short)(u >> 16);
}
__device__ __forceinline__ float bf2f(unsigned short s) {
  return __builtin_bit_cast(float, (unsigned)s << 16);
}

// ---------------------------------------------------------------------------
// K1 "pre": fused block-segments
//   [0,440)   w2 transpose f32->bf16 [ch][128] via LDS 32x32 tiles
//   [440,472) per-image point binning (counts + plist)
//   [472,600) loss-mask ones fill
//   [600,728) pe1 split-K=4 partial GEMM: pe(256x1280)@w1s(1280x512) -> part[4][256][512]
__global__ __launch_bounds__(256) void k_pre(const float* __restrict__ w2_0,
                                             const float* __restrict__ w2_1,
                                             const float* __restrict__ w2_2,
                                             const float* __restrict__ w2_3,
                                             unsigned short* __restrict__ W2T0,
                                             unsigned short* __restrict__ W2T1,
                                             unsigned short* __restrict__ W2T2,
                                             unsigned short* __restrict__ W2T3,
                                             const float* __restrict__ kp,
                                             const int* __restrict__ subsets,
                                             int* __restrict__ counts,
                                             int* __restrict__ plist,
                                             float* __restrict__ lossm,
                                             const float* __restrict__ pe,
                                             const float* __restrict__ w1s,
                                             float* __restrict__ part) {
  __shared__ __align__(16) char smem[41984];
  int b = blockIdx.x;
  int tid = threadIdx.x;
  if (b < 440) {
    // ---- transpose segment
    float (*ts)[33] = (float(*)[33])smem;
    const float* w2;
    unsigned short* wt;
    int ch, local;
    if (b < 40) { w2 = w2_0; wt = W2T0; ch = 320; local = b; }
    else if (b < 120) { w2 = w2_1; wt = W2T1; ch = 640; local = b - 40; }
    else if (b < 280) { w2 = w2_2; wt = W2T2; ch = 1280; local = b - 120; }
    else { w2 = w2_3; wt = W2T3; ch = 1280; local = b - 280; }
    int ctiles = ch >> 5;
    int mt = local / ctiles, ct = local % ctiles;
    int m0 = mt * 32, c0 = ct * 32;
    int i = tid >> 5, j = tid & 31;
#pragma unroll
    for (int r = 0; r < 4; ++r) {
      int m = r * 8 + i;
      ts[m][j] = w2[(size_t)(m0 + m) * ch + c0 + j];
    }
    __syncthreads();
#pragma unroll
    for (int r = 0; r < 4; ++r) {
      int c = r * 8 + i;
      wt[(size_t)(c0 + c) * 128 + m0 + j] = f2bf(ts[j][c]);
    }
  } else if (b < 472) {
    // ---- binning segment
    int bf = b - 440;
    int* lcnt = (int*)smem;
    for (int i = tid; i < 1024; i += 256) lcnt[i] = 0;
    __syncthreads();
    if (tid < NPT) {
      int p = bf * NPT + tid;
      float kx = kp[2 * p], ky = kp[2 * p + 1];
      int sub = subsets[p];
      if (fminf(kx, ky) >= 0.f && sub != -1) {
        int px = (int)floorf(kx * 32.f);
        px = px < 0 ? 0 : (px > 31 ? 31 : px);
        int py = (int)floorf(ky * 32.f);
        py = py < 0 ? 0 : (py > 31 ? 31 : py);
        int cell = py * 32 + px;
        int slot = atomicAdd(&lcnt[cell], 1);
        if (slot < 32) plist[((size_t)bf * 1024 + cell) * 32 + slot] = tid;
      }
    }
    __syncthreads();
    for (int i = tid; i < 1024; i += 256) counts[bf * 1024 + i] = lcnt[i];
  } else if (b < 600) {
    // ---- ones segment
    int idx = (b - 472) * 256 + tid;
    *reinterpret_cast<float4*>(lossm + (size_t)idx * 4) = make_float4(1.f, 1.f, 1.f, 1.f);
  } else {
    // ---- pe1 partial-GEMM segment: 128 blocks = 8 ntiles x 4 mtiles x 4 ksplits
    int local = b - 600;
    int nt = local & 7, mt = (local >> 3) & 3, kz = local >> 5;
    int n0 = nt * 64, m0 = mt * 64;
    float* As = (float*)smem;            // [64][84]
    float* Bs = (float*)(smem + 21504);  // [80][64]
    int l = n0 >> 7, m0c = n0 & 127;
    const float* wbase = w1s + (size_t)l * CC * MID + m0c;
    int tx = tid & 15, ty = tid >> 4;
    float acc[4][4] = {};
    for (int sub = 0; sub < 4; ++sub) {
      int kc0 = kz * 320 + sub * 80;
      __syncthreads();
      for (int idx = tid; idx < 64 * 20; idx += 256) {
        int row = idx / 20, kk = idx % 20;
        float4 v = *reinterpret_cast<const float4*>(&pe[(size_t)(m0 + row) * CC + kc0 + kk * 4]);
        *reinterpret_cast<float4*>(&As[row * 84 + kk * 4]) = v;
      }
      for (int idx = tid; idx < 80 * 16; idx += 256) {
        int k = idx / 16, cg = idx % 16;
        float4 v = *reinterpret_cast<const float4*>(&wbase[(size_t)(kc0 + k) * MID + cg * 4]);
        *reinterpret_cast<float4*>(&Bs[k * 64 + cg * 4]) = v;
      }
      __syncthreads();
      for (int k4 = 0; k4 < 80; k4 += 4) {
        float4 a[4], bb[4];
#pragma unroll
        for (int i = 0; i < 4; ++i)
          a[i] = *reinterpret_cast<const float4*>(&As[(ty * 4 + i) * 84 + k4]);
#pragma unroll
        for (int kk = 0; kk < 4; ++kk)
          bb[kk] = *reinterpret_cast<const float4*>(&Bs[(k4 + kk) * 64 + tx * 4]);
#pragma unroll
        for (int i = 0; i < 4; ++i) {
          float av[4] = {a[i].x, a[i].y, a[i].z, a[i].w};
#pragma unroll
          for (int kk = 0; kk < 4; ++kk) {
            acc[i][0] = fmaf(av[kk], bb[kk].x, acc[i][0]);
            acc[i][1] = fmaf(av[kk], bb[kk].y, acc[i][1]);
            acc[i][2] = fmaf(av[kk], bb[kk].z, acc[i][2]);
            acc[i][3] = fmaf(av[kk], bb[kk].w, acc[i][3]);
          }
        }
      }
    }
    float* pb = part + (size_t)kz * 131072;
#pragma unroll
    for (int i = 0; i < 4; ++i) {
      float4 v = make_float4(acc[i][0], acc[i][1], acc[i][2], acc[i][3]);
      *reinterpret_cast<float4*>(&pb[(size_t)(m0 + ty * 4 + i) * 512 + n0 + tx * 4]) = v;
    }
  }
}

// ---------------------------------------------------------------------------
// K2: non-empty cells: H[l][cell][m] = bf16(silu(mean + b1)); sums the 4
// split-K partials inline (pe1 never materialized). Empty cells skipped.
__global__ __launch_bounds__(256) void k_hid2(const float* __restrict__ part,
                                              const int* __restrict__ counts,
                                              const int* __restrict__ plist,
                                              const float* __restrict__ b1s,
                                              unsigned short* __restrict__ H) {
  __shared__ int lst[32];
  int t = threadIdx.x;
  for (int q = 0; q < 8; ++q) {
    int cell = blockIdx.x * 8 + q;
    int c = counts[cell];
    if (c == 0) continue;  // block-uniform
    __syncthreads();
    int cu = c < 32 ? c : 32;
    if (t < cu) lst[t] = plist[(size_t)cell * 32 + t];
    __syncthreads();
    int b = cell >> 14;
    float invc = 1.f / (float)c;
    float s0 = 0.f, s1 = 0.f;
    for (int i = 0; i < cu; ++i) {
      const float* rp = part + (size_t)(b * NPT + lst[i]) * 512;
      s0 += rp[t] + rp[131072 + t] + rp[262144 + t] + rp[393216 + t];
      s1 += rp[t + 256] + rp[131072 + t + 256] + rp[262144 + t + 256] + rp[393216 + t + 256];
    }
    float t0 = s0 * invc + b1s[t];
    float t1 = s1 * invc + b1s[t + 256];
    t0 = t0 / (1.f + expf(-t0));
    t1 = t1 / (1.f + expf(-t1));
    int l0 = t >> 7, m = t & 127;
    H[(size_t)l0 * 4194304 + (size_t)cell * 128 + m] = f2bf(t0);
    H[(size_t)(l0 + 2) * 4194304 + (size_t)cell * 128 + m] = f2bf(t1);
  }
}

// ---------------------------------------------------------------------------
// K3: merged MFMA GEMM, all 4 levels; A-staging does count-gated zero-fill
// (level 0) or on-the-fly 2x2 aggregation (levels 1-3). 5 ch-tiles per block.
template <int LOGW, int SCALE, int OFF, bool GATED>
__device__ __forceinline__ void mgemm_body(int bx, int byg,
                                           const unsigned short* __restrict__ Hl,
                                           const unsigned short* __restrict__ W2,
                                           const float* __restrict__ b2,
                                           const int* __restrict__ counts,
                                           float* __restrict__ out, int ch,
                                           unsigned short* Asl, unsigned short* Wsl,
                                           float* Ssl, float* Mnl) {
  const int W = 1 << LOGW;
  const int SDIM = 1 << (2 * LOGW);
  int r0 = bx * 64;
  int img = r0 >> (2 * LOGW);
  int tid = threadIdx.x;
  if (GATED) {
    for (int idx = tid; idx < 1024; idx += 256) {
      int r = idx >> 4, g = idx & 15;
      uint4 v = make_uint4(0u, 0u, 0u, 0u);
      if (counts[r0 + r] > 0)
        v = *reinterpret_cast<const uint4*>(Hl + (size_t)(r0 + r) * 128 + g * 8);
      *reinterpret_cast<uint4*>(&Asl[r * 128 + ((g ^ (r & 7)) << 3)]) = v;
    }
    if (tid < 64) {
      float mv = counts[r0 + tid] > 0 ? 1.f : 0.f;
      Ssl[tid] = mv;
      Mnl[tid] = mv;
    }
  } else {
    for (int idx = tid; idx < 1024; idx += 256) {
      int r = idx >> 4, g = idx & 15;
      int cr = r0 + r;
      int sp = cr & (SDIM - 1);
      int y = sp >> LOGW, x = sp & (W - 1);
      int c00 = (cr >> (2 * LOGW)) * 1024 + (SCALE * y + OFF) * 32 + (SCALE * x + OFF);
      int n00 = counts[c00], n01 = counts[c00 + 1];
      int n10 = counts[c00 + 32], n11 = counts[c00 + 33];
      float acc[8] = {};
#define ADDCELL(CELL)                                                      \
      {                                                                    \
        uint4 hv = *reinterpret_cast<const uint4*>(Hl + (size_t)(CELL) * 128 + g * 8); \
        unsigned uu[4] = {hv.x, hv.y, hv.z, hv.w};                         \
        _Pragma("unroll")                                                  \
        for (int qq = 0; qq < 4; ++qq) {                                   \
          acc[2 * qq] += __builtin_bit_cast(float, uu[qq] << 16);          \
          acc[2 * qq + 1] += __builtin_bit_cast(float, uu[qq] & 0xFFFF0000u); \
        }                                                                  \
      }
      if (n00 > 0) ADDCELL(c00)
      if (n01 > 0) ADDCELL(c00 + 1)
      if (n10 > 0) ADDCELL(c00 + 32)
      if (n11 > 0) ADDCELL(c00 + 33)
#undef ADDCELL
      unsigned short pk[8];
#pragma unroll
      for (int qq = 0; qq < 8; ++qq) pk[qq] = f2bf(0.25f * acc[qq]);
      uint4 v;
      v.x = (unsigned)pk[0] | ((unsigned)pk[1] << 16);
      v.y = (unsigned)pk[2] | ((unsigned)pk[3] << 16);
      v.z = (unsigned)pk[4] | ((unsigned)pk[5] << 16);
      v.w = (unsigned)pk[6] | ((unsigned)pk[7] << 16);
      *reinterpret_cast<uint4*>(&Asl[r * 128 + ((g ^ (r & 7)) << 3)]) = v;
    }
    if (tid < 64) {
      int cr = r0 + tid;
      int sp = cr & (SDIM - 1);
      int y = sp >> LOGW, x = sp & (W - 1);
      int ib = (cr >> (2 * LOGW)) * 1024;
      int c00 = ib + (SCALE * y + OFF) * 32 + (SCALE * x + OFF);
      float sm = (counts[c00] > 0 ? 1.f : 0.f) + (counts[c00 + 1] > 0 ? 1.f : 0.f) +
                 (counts[c00 + 32] > 0 ? 1.f : 0.f) + (counts[c00 + 33] > 0 ? 1.f : 0.f);
      Ssl[tid] = 0.25f * sm;
      Mnl[tid] = counts[ib + (SCALE * y) * 32 + SCALE * x] > 0 ? 1.f : 0.f;
    }
  }
  int lane = tid & 63;
  int wave = tid >> 6;
  int lr = lane & 15, lk = lane >> 4;
  int choff = (wave & 1) * 32, spoff = (wave >> 1) * 32;

  for (int it = 0; it < 5; ++it) {
    int k0 = (byg * 5 + it) * 64;
    __syncthreads();
    for (int idx = tid; idx < 1024; idx += 256) {
      int r = idx >> 4, g = idx & 15;
      uint4 v = *reinterpret_cast<const uint4*>(W2 + (size_t)(k0 + r) * 128 + g * 8);
      *reinterpret_cast<uint4*>(&Wsl[r * 128 + ((g ^ (r & 7)) << 3)]) = v;
    }
    __syncthreads();
    f32x4 acc00 = {0.f, 0.f, 0.f, 0.f}, acc01 = acc00, acc10 = acc00, acc11 = acc00;
#pragma unroll
    for (int kk = 0; kk < 128; kk += 32) {
      int gbase = (kk >> 3) + lk;
      int r0w = choff + lr, r1w = choff + 16 + lr;
      int r0a = spoff + lr, r1a = spoff + 16 + lr;
      bf16x8 wf0 = *reinterpret_cast<const bf16x8*>(&Wsl[r0w * 128 + ((gbase ^ (r0w & 7)) << 3)]);
      bf16x8 wf1 = *reinterpret_cast<const bf16x8*>(&Wsl[r1w * 128 + ((gbase ^ (r1w & 7)) << 3)]);
      bf16x8 af0 = *reinterpret_cast<const bf16x8*>(&Asl[r0a * 128 + ((gbase ^ (r0a & 7)) << 3)]);
      bf16x8 af1 = *reinterpret_cast<const bf16x8*>(&Asl[r1a * 128 + ((gbase ^ (r1a & 7)) << 3)]);
      acc00 = __builtin_amdgcn_mfma_f32_16x16x32_bf16(wf0, af0, acc00, 0, 0, 0);
      acc01 = __builtin_amdgcn_mfma_f32_16x16x32_bf16(wf0, af1, acc01, 0, 0, 0);
      acc10 = __builtin_amdgcn_mfma_f32_16x16x32_bf16(wf1, af0, acc10, 0, 0, 0);
      acc11 = __builtin_amdgcn_mfma_f32_16x16x32_bf16(wf1, af1, acc11, 0, 0, 0);
    }
#define EPI(ACC, CI, SI)                                                          \
    {                                                                             \
      int spl = spoff + (SI) * 16 + lr;                                           \
      int absrow = r0 + spl;                                                      \
      float ss = Ssl[spl], mn = Mnl[spl];                                         \
      float* op = out + (size_t)img * ch * SDIM + (absrow & (SDIM - 1));          \
      _Pragma("unroll")                                                           \
      for (int rr = 0; rr < 4; ++rr) {                                            \
        int chl = k0 + choff + (CI) * 16 + lk * 4 + rr;                           \
        op[(size_t)chl * SDIM] = mn * (ACC[rr] + ss * b2[chl]);                   \
      }                                                                           \
    }
    EPI(acc00, 0, 0)
    EPI(acc01, 0, 1)
    EPI(acc10, 1, 0)
    EPI(acc11, 1, 1)
#undef EPI
  }
}

__global__ __launch_bounds__(256) void k_mgemm_all(
    const unsigned short* __restrict__ H,
    const unsigned short* __restrict__ W2T0, const unsigned short* __restrict__ W2T1,
    const unsigned short* __restrict__ W2T2, const unsigned short* __restrict__ W2T3,
    const float* __restrict__ b20, const float* __restrict__ b21,
    const float* __restrict__ b22, const float* __restrict__ b23,
    const int* __restrict__ counts,
    float* __restrict__ out0, float* __restrict__ out1,
    float* __restrict__ out2, float* __restrict__ out3) {
  __shared__ __align__(16) unsigned short Asl[64 * 128];
  __shared__ __align__(16) unsigned short Wsl[64 * 128];
  __shared__ float Ssl[64], Mnl[64];
  int b = blockIdx.x;
  if (b < 512) {
    mgemm_body<5, 1, 0, true>(b, 0, H, W2T0, b20, counts, out0, 320, Asl, Wsl, Ssl, Mnl);
  } else if (b < 768) {
    int l = b - 512;
    mgemm_body<4, 2, 0, false>(l & 127, l >> 7, H + 4194304, W2T1, b21, counts, out1, 640,
                               Asl, Wsl, Ssl, Mnl);
  } else if (b < 896) {
    int l = b - 768;
    mgemm_body<3, 4, 1, false>(l & 31, l >> 5, H + 2 * 4194304, W2T2, b22, counts, out2, 1280,
                               Asl, Wsl, Ssl, Mnl);
  } else {
    int l = b - 896;
    mgemm_body<3, 4, 1, false>(l & 31, l >> 5, H + 3 * 4194304, W2T3, b23, counts, out3, 1280,
                               Asl, Wsl, Ssl, Mnl);
  }
}

// ---------------------------------------------------------------------------
extern "C" void kernel_launch(void* const* d_in, const int* in_sizes, int n_in,
                              void* d_out, int out_size, void* d_ws, size_t ws_size,
                              hipStream_t stream) {
  const float* pe = (const float*)d_in[0];
  const float* kp = (const float*)d_in[1];
  const int* subsets = (const int*)d_in[2];
  const float* w1s = (const float*)d_in[4];
  const float* b1s = (const float*)d_in[5];
  const float* w2l[4] = {(const float*)d_in[6], (const float*)d_in[8],
                         (const float*)d_in[10], (const float*)d_in[12]};
  const float* b2l[4] = {(const float*)d_in[7], (const float*)d_in[9],
                         (const float*)d_in[11], (const float*)d_in[13]};
  float* out = (float*)d_out;

  // workspace layout
  float* part = (float*)d_ws;                        // 4*131072 f32
  int* counts = (int*)(part + 524288);               // 32768
  int* plist = counts + 32768;                       // 32768*32
  unsigned short* H = (unsigned short*)(plist + 1048576);  // 4*4194304 bf16
  unsigned short* W2T0 = H + 16777216;               // 320*128
  unsigned short* W2T1 = W2T0 + 40960;               // 640*128
  unsigned short* W2T2 = W2T1 + 81920;               // 1280*128
  unsigned short* W2T3 = W2T2 + 163840;              // 1280*128

  float* out0 = out;                  // (2,16,320,32,32)
  float* out1 = out + 10485760;       // (2,16,640,16,16)
  float* out2 = out + 15728640;       // (2,16,1280,8,8)
  float* out3 = out + 18350080;       // (2,16,1280,8,8)
  float* lossm = out + 20971520;      // (2,16,4,32,32)

  k_pre<<<dim3(728), dim3(256), 0, stream>>>(w2l[0], w2l[1], w2l[2], w2l[3],
                                             W2T0, W2T1, W2T2, W2T3,
                                             kp, subsets, counts, plist, lossm,
                                             pe, w1s, part);
  k_hid2<<<dim3(4096), dim3(256), 0, stream>>>(part, counts, plist, b1s, H);
  k_mgemm_all<<<dim3(1024), dim3(256), 0, stream>>>(H, W2T0, W2T1, W2T2, W2T3,
                                                    b2l[0], b2l[1], b2l[2], b2l[3],
                                                    counts, out0, out1, out2, out3);
}

// Round 6
// 45.858 us; speedup vs baseline: 1.2819x; 1.2819x over previous
//
#include <hip/hip_runtime.h>
#include <cstdint>
#include <cstddef>

#define BB 2
#define FF 16
#define NPT 128
#define CC 1280
#define MID 128

typedef __attribute__((ext_vector_type(8))) short bf16x8;
typedef __attribute__((ext_vector_type(4))) float f32x4;

__device__ __forceinline__ unsigned short f2bf(float f) {
  unsigned u = __builtin_bit_cast(unsigned, f);
  u += 0x7FFFu + ((u >> 16) & 1u);  // RNE
  return (unsigned short)(u >> 16);
}
__device__ __forceinline__ float bf2f(unsigned short s) {
  return __builtin_bit_cast(float, (unsigned)s << 16);
}

// ---------------------------------------------------------------------------
// K1 "pre": fused block-segments (long poles first in dispatch order)
//   [0,128)   pe1 MFMA split-K=4 partials: pe(256x1280)@w1s(1280x512) -> part[4][256][512]
//             (f32->bf16 conversion fused into LDS staging)
//   [128,160) per-image point binning (counts + plist)
//   [160,600) w2 transpose f32->bf16 [ch][128] via LDS 32x32 tiles
//   [600,728) loss-mask ones fill
__global__ __launch_bounds__(256) void k_pre(const float* __restrict__ w2_0,
                                             const float* __restrict__ w2_1,
                                             const float* __restrict__ w2_2,
                                             const float* __restrict__ w2_3,
                                             unsigned short* __restrict__ W2T0,
                                             unsigned short* __restrict__ W2T1,
                                             unsigned short* __restrict__ W2T2,
                                             unsigned short* __restrict__ W2T3,
                                             const float* __restrict__ kp,
                                             const int* __restrict__ subsets,
                                             int* __restrict__ counts,
                                             int* __restrict__ plist,
                                             float* __restrict__ lossm,
                                             const float* __restrict__ pe,
                                             const float* __restrict__ w1s,
                                             float* __restrict__ part) {
  __shared__ __align__(16) char smem[17408];
  int b = blockIdx.x;
  int tid = threadIdx.x;
  if (b < 128) {
    // ---- pe1 MFMA segment: 128 units = 8 ntiles x 4 mtiles x 4 ksplits (K=320)
    unsigned short* Asl = (unsigned short*)smem;          // [64 pe-rows][64 k] bf16
    unsigned short* Bsl = (unsigned short*)(smem + 8192); // [64 out-cols][64 k] bf16
    int nt = b & 7, mt = (b >> 3) & 3, kz = b >> 5;
    int n0 = nt * 64, m0 = mt * 64;
    int l = n0 >> 7, m0c = n0 & 127;
    const float* wbase = w1s + (size_t)l * CC * MID + m0c;
    int lane = tid & 63;
    int wave = tid >> 6;
    int lr = lane & 15, lk = lane >> 4;
    int choff = (wave & 1) * 32, spoff = (wave >> 1) * 32;  // choff: out-col, spoff: pe-row
    f32x4 acc00 = {0.f, 0.f, 0.f, 0.f}, acc01 = acc00, acc10 = acc00, acc11 = acc00;
    for (int sub = 0; sub < 5; ++sub) {
      int kc0 = kz * 320 + sub * 64;
      __syncthreads();
      // stage A: pe rows, f32 -> bf16. 512 granules (r,g): 8 bf16 each.
      for (int u = tid; u < 512; u += 256) {
        int r = u >> 3, g = u & 7;
        const float* src = pe + (size_t)(m0 + r) * CC + kc0 + g * 8;
        float4 v0 = *reinterpret_cast<const float4*>(src);
        float4 v1 = *reinterpret_cast<const float4*>(src + 4);
        uint4 pk;
        pk.x = (unsigned)f2bf(v0.x) | ((unsigned)f2bf(v0.y) << 16);
        pk.y = (unsigned)f2bf(v0.z) | ((unsigned)f2bf(v0.w) << 16);
        pk.z = (unsigned)f2bf(v1.x) | ((unsigned)f2bf(v1.y) << 16);
        pk.w = (unsigned)f2bf(v1.z) | ((unsigned)f2bf(v1.w) << 16);
        *reinterpret_cast<uint4*>(&Asl[r * 64 + ((g ^ (r & 7)) << 3)]) = pk;
      }
      // stage B: out-col rows (transposed gather from w1s), f32 -> bf16.
      for (int u = tid; u < 512; u += 256) {
        int r = u & 63, gg = u >> 6;
        float vv[8];
#pragma unroll
        for (int j = 0; j < 8; ++j)
          vv[j] = wbase[(size_t)(kc0 + gg * 8 + j) * MID + r];
        uint4 pk;
        pk.x = (unsigned)f2bf(vv[0]) | ((unsigned)f2bf(vv[1]) << 16);
        pk.y = (unsigned)f2bf(vv[2]) | ((unsigned)f2bf(vv[3]) << 16);
        pk.z = (unsigned)f2bf(vv[4]) | ((unsigned)f2bf(vv[5]) << 16);
        pk.w = (unsigned)f2bf(vv[6]) | ((unsigned)f2bf(vv[7]) << 16);
        *reinterpret_cast<uint4*>(&Bsl[r * 64 + ((gg ^ (r & 7)) << 3)]) = pk;
      }
      __syncthreads();
#pragma unroll
      for (int kk = 0; kk < 64; kk += 32) {
        int gbase = (kk >> 3) + lk;
        int r0w = choff + lr, r1w = choff + 16 + lr;
        int r0a = spoff + lr, r1a = spoff + 16 + lr;
        bf16x8 wf0 = *reinterpret_cast<const bf16x8*>(&Bsl[r0w * 64 + ((gbase ^ (r0w & 7)) << 3)]);
        bf16x8 wf1 = *reinterpret_cast<const bf16x8*>(&Bsl[r1w * 64 + ((gbase ^ (r1w & 7)) << 3)]);
        bf16x8 af0 = *reinterpret_cast<const bf16x8*>(&Asl[r0a * 64 + ((gbase ^ (r0a & 7)) << 3)]);
        bf16x8 af1 = *reinterpret_cast<const bf16x8*>(&Asl[r1a * 64 + ((gbase ^ (r1a & 7)) << 3)]);
        acc00 = __builtin_amdgcn_mfma_f32_16x16x32_bf16(wf0, af0, acc00, 0, 0, 0);
        acc01 = __builtin_amdgcn_mfma_f32_16x16x32_bf16(wf0, af1, acc01, 0, 0, 0);
        acc10 = __builtin_amdgcn_mfma_f32_16x16x32_bf16(wf1, af0, acc10, 0, 0, 0);
        acc11 = __builtin_amdgcn_mfma_f32_16x16x32_bf16(wf1, af1, acc11, 0, 0, 0);
      }
    }
    // store: part[kz][pe-row m0+spl][out-col n0+chl]
    float* pb = part + (size_t)kz * 131072;
#define PEPI(ACC, CI, SI)                                                    \
    {                                                                        \
      int spl = spoff + (SI) * 16 + lr;                                      \
      _Pragma("unroll")                                                      \
      for (int rr = 0; rr < 4; ++rr) {                                       \
        int chl = choff + (CI) * 16 + lk * 4 + rr;                           \
        pb[(size_t)(m0 + spl) * 512 + n0 + chl] = ACC[rr];                   \
      }                                                                      \
    }
    PEPI(acc00, 0, 0)
    PEPI(acc01, 0, 1)
    PEPI(acc10, 1, 0)
    PEPI(acc11, 1, 1)
#undef PEPI
  } else if (b < 160) {
    // ---- binning segment
    int bf = b - 128;
    int* lcnt = (int*)smem;
    for (int i = tid; i < 1024; i += 256) lcnt[i] = 0;
    __syncthreads();
    if (tid < NPT) {
      int p = bf * NPT + tid;
      float kx = kp[2 * p], ky = kp[2 * p + 1];
      int sub = subsets[p];
      if (fminf(kx, ky) >= 0.f && sub != -1) {
        int px = (int)floorf(kx * 32.f);
        px = px < 0 ? 0 : (px > 31 ? 31 : px);
        int py = (int)floorf(ky * 32.f);
        py = py < 0 ? 0 : (py > 31 ? 31 : py);
        int cell = py * 32 + px;
        int slot = atomicAdd(&lcnt[cell], 1);
        if (slot < 32) plist[((size_t)bf * 1024 + cell) * 32 + slot] = tid;
      }
    }
    __syncthreads();
    for (int i = tid; i < 1024; i += 256) counts[bf * 1024 + i] = lcnt[i];
  } else if (b < 600) {
    // ---- w2 transpose segment
    float (*ts)[33] = (float(*)[33])smem;
    int local = b - 160;
    const float* w2;
    unsigned short* wt;
    int ch;
    if (local < 40) { w2 = w2_0; wt = W2T0; ch = 320; }
    else if (local < 120) { w2 = w2_1; wt = W2T1; ch = 640; local -= 40; }
    else if (local < 280) { w2 = w2_2; wt = W2T2; ch = 1280; local -= 120; }
    else { w2 = w2_3; wt = W2T3; ch = 1280; local -= 280; }
    int ctiles = ch >> 5;
    int mt = local / ctiles, ct = local % ctiles;
    int m0 = mt * 32, c0 = ct * 32;
    int i = tid >> 5, j = tid & 31;
#pragma unroll
    for (int r = 0; r < 4; ++r) {
      int m = r * 8 + i;
      ts[m][j] = w2[(size_t)(m0 + m) * ch + c0 + j];
    }
    __syncthreads();
#pragma unroll
    for (int r = 0; r < 4; ++r) {
      int c = r * 8 + i;
      wt[(size_t)(c0 + c) * 128 + m0 + j] = f2bf(ts[j][c]);
    }
  } else {
    // ---- ones segment
    int idx = (b - 600) * 256 + tid;
    *reinterpret_cast<float4*>(lossm + (size_t)idx * 4) = make_float4(1.f, 1.f, 1.f, 1.f);
  }
}

// ---------------------------------------------------------------------------
// K2: non-empty cells: H[l][cell][m] = bf16(silu(mean + b1)); sums the 4
// split-K partials inline. Empty cells skipped (H stale there, never read).
__global__ __launch_bounds__(256) void k_hid2(const float* __restrict__ part,
                                              const int* __restrict__ counts,
                                              const int* __restrict__ plist,
                                              const float* __restrict__ b1s,
                                              unsigned short* __restrict__ H) {
  __shared__ int lst[32];
  int t = threadIdx.x;
  for (int q = 0; q < 8; ++q) {
    int cell = blockIdx.x * 8 + q;
    int c = counts[cell];
    if (c == 0) continue;  // block-uniform
    __syncthreads();
    int cu = c < 32 ? c : 32;
    if (t < cu) lst[t] = plist[(size_t)cell * 32 + t];
    __syncthreads();
    int b = cell >> 14;
    float invc = 1.f / (float)c;
    float s0 = 0.f, s1 = 0.f;
    for (int i = 0; i < cu; ++i) {
      const float* rp = part + (size_t)(b * NPT + lst[i]) * 512;
      s0 += rp[t] + rp[131072 + t] + rp[262144 + t] + rp[393216 + t];
      s1 += rp[t + 256] + rp[131072 + t + 256] + rp[262144 + t + 256] + rp[393216 + t + 256];
    }
    float t0 = s0 * invc + b1s[t];
    float t1 = s1 * invc + b1s[t + 256];
    t0 = t0 / (1.f + expf(-t0));
    t1 = t1 / (1.f + expf(-t1));
    int l0 = t >> 7, m = t & 127;
    H[(size_t)l0 * 4194304 + (size_t)cell * 128 + m] = f2bf(t0);
    H[(size_t)(l0 + 2) * 4194304 + (size_t)cell * 128 + m] = f2bf(t1);
  }
}

// ---------------------------------------------------------------------------
// K3: merged MFMA GEMM, all 4 levels; A-staging does count-gated zero-fill
// (level 0) or on-the-fly 2x2 aggregation (levels 1-3). 5 ch-tiles per block.
template <int LOGW, int SCALE, int OFF, bool GATED>
__device__ __forceinline__ void mgemm_body(int bx, int byg,
                                           const unsigned short* __restrict__ Hl,
                                           const unsigned short* __restrict__ W2,
                                           const float* __restrict__ b2,
                                           const int* __restrict__ counts,
                                           float* __restrict__ out, int ch,
                                           unsigned short* Asl, unsigned short* Wsl,
                                           float* Ssl, float* Mnl) {
  const int W = 1 << LOGW;
  const int SDIM = 1 << (2 * LOGW);
  int r0 = bx * 64;
  int img = r0 >> (2 * LOGW);
  int tid = threadIdx.x;
  if (GATED) {
    for (int idx = tid; idx < 1024; idx += 256) {
      int r = idx >> 4, g = idx & 15;
      uint4 v = make_uint4(0u, 0u, 0u, 0u);
      if (counts[r0 + r] > 0)
        v = *reinterpret_cast<const uint4*>(Hl + (size_t)(r0 + r) * 128 + g * 8);
      *reinterpret_cast<uint4*>(&Asl[r * 128 + ((g ^ (r & 7)) << 3)]) = v;
    }
    if (tid < 64) {
      float mv = counts[r0 + tid] > 0 ? 1.f : 0.f;
      Ssl[tid] = mv;
      Mnl[tid] = mv;
    }
  } else {
    for (int idx = tid; idx < 1024; idx += 256) {
      int r = idx >> 4, g = idx & 15;
      int cr = r0 + r;
      int sp = cr & (SDIM - 1);
      int y = sp >> LOGW, x = sp & (W - 1);
      int c00 = (cr >> (2 * LOGW)) * 1024 + (SCALE * y + OFF) * 32 + (SCALE * x + OFF);
      int n00 = counts[c00], n01 = counts[c00 + 1];
      int n10 = counts[c00 + 32], n11 = counts[c00 + 33];
      float acc[8] = {};
#define ADDCELL(CELL)                                                      \
      {                                                                    \
        uint4 hv = *reinterpret_cast<const uint4*>(Hl + (size_t)(CELL) * 128 + g * 8); \
        unsigned uu[4] = {hv.x, hv.y, hv.z, hv.w};                         \
        _Pragma("unroll")                                                  \
        for (int qq = 0; qq < 4; ++qq) {                                   \
          acc[2 * qq] += __builtin_bit_cast(float, uu[qq] << 16);          \
          acc[2 * qq + 1] += __builtin_bit_cast(float, uu[qq] & 0xFFFF0000u); \
        }                                                                  \
      }
      if (n00 > 0) ADDCELL(c00)
      if (n01 > 0) ADDCELL(c00 + 1)
      if (n10 > 0) ADDCELL(c00 + 32)
      if (n11 > 0) ADDCELL(c00 + 33)
#undef ADDCELL
      unsigned short pk[8];
#pragma unroll
      for (int qq = 0; qq < 8; ++qq) pk[qq] = f2bf(0.25f * acc[qq]);
      uint4 v;
      v.x = (unsigned)pk[0] | ((unsigned)pk[1] << 16);
      v.y = (unsigned)pk[2] | ((unsigned)pk[3] << 16);
      v.z = (unsigned)pk[4] | ((unsigned)pk[5] << 16);
      v.w = (unsigned)pk[6] | ((unsigned)pk[7] << 16);
      *reinterpret_cast<uint4*>(&Asl[r * 128 + ((g ^ (r & 7)) << 3)]) = v;
    }
    if (tid < 64) {
      int cr = r0 + tid;
      int sp = cr & (SDIM - 1);
      int y = sp >> LOGW, x = sp & (W - 1);
      int ib = (cr >> (2 * LOGW)) * 1024;
      int c00 = ib + (SCALE * y + OFF) * 32 + (SCALE * x + OFF);
      float sm = (counts[c00] > 0 ? 1.f : 0.f) + (counts[c00 + 1] > 0 ? 1.f : 0.f) +
                 (counts[c00 + 32] > 0 ? 1.f : 0.f) + (counts[c00 + 33] > 0 ? 1.f : 0.f);
      Ssl[tid] = 0.25f * sm;
      Mnl[tid] = counts[ib + (SCALE * y) * 32 + SCALE * x] > 0 ? 1.f : 0.f;
    }
  }
  int lane = tid & 63;
  int wave = tid >> 6;
  int lr = lane & 15, lk = lane >> 4;
  int choff = (wave & 1) * 32, spoff = (wave >> 1) * 32;

  for (int it = 0; it < 5; ++it) {
    int k0 = (byg * 5 + it) * 64;
    __syncthreads();
    for (int idx = tid; idx < 1024; idx += 256) {
      int r = idx >> 4, g = idx & 15;
      uint4 v = *reinterpret_cast<const uint4*>(W2 + (size_t)(k0 + r) * 128 + g * 8);
      *reinterpret_cast<uint4*>(&Wsl[r * 128 + ((g ^ (r & 7)) << 3)]) = v;
    }
    __syncthreads();
    f32x4 acc00 = {0.f, 0.f, 0.f, 0.f}, acc01 = acc00, acc10 = acc00, acc11 = acc00;
#pragma unroll
    for (int kk = 0; kk < 128; kk += 32) {
      int gbase = (kk >> 3) + lk;
      int r0w = choff + lr, r1w = choff + 16 + lr;
      int r0a = spoff + lr, r1a = spoff + 16 + lr;
      bf16x8 wf0 = *reinterpret_cast<const bf16x8*>(&Wsl[r0w * 128 + ((gbase ^ (r0w & 7)) << 3)]);
      bf16x8 wf1 = *reinterpret_cast<const bf16x8*>(&Wsl[r1w * 128 + ((gbase ^ (r1w & 7)) << 3)]);
      bf16x8 af0 = *reinterpret_cast<const bf16x8*>(&Asl[r0a * 128 + ((gbase ^ (r0a & 7)) << 3)]);
      bf16x8 af1 = *reinterpret_cast<const bf16x8*>(&Asl[r1a * 128 + ((gbase ^ (r1a & 7)) << 3)]);
      acc00 = __builtin_amdgcn_mfma_f32_16x16x32_bf16(wf0, af0, acc00, 0, 0, 0);
      acc01 = __builtin_amdgcn_mfma_f32_16x16x32_bf16(wf0, af1, acc01, 0, 0, 0);
      acc10 = __builtin_amdgcn_mfma_f32_16x16x32_bf16(wf1, af0, acc10, 0, 0, 0);
      acc11 = __builtin_amdgcn_mfma_f32_16x16x32_bf16(wf1, af1, acc11, 0, 0, 0);
    }
#define EPI(ACC, CI, SI)                                                          \
    {                                                                             \
      int spl = spoff + (SI) * 16 + lr;                                           \
      int absrow = r0 + spl;                                                      \
      float ss = Ssl[spl], mn = Mnl[spl];                                         \
      float* op = out + (size_t)img * ch * SDIM + (absrow & (SDIM - 1));          \
      _Pragma("unroll")                                                           \
      for (int rr = 0; rr < 4; ++rr) {                                            \
        int chl = k0 + choff + (CI) * 16 + lk * 4 + rr;                           \
        op[(size_t)chl * SDIM] = mn * (ACC[rr] + ss * b2[chl]);                   \
      }                                                                           \
    }
    EPI(acc00, 0, 0)
    EPI(acc01, 0, 1)
    EPI(acc10, 1, 0)
    EPI(acc11, 1, 1)
#undef EPI
  }
}

__global__ __launch_bounds__(256) void k_mgemm_all(
    const unsigned short* __restrict__ H,
    const unsigned short* __restrict__ W2T0, const unsigned short* __restrict__ W2T1,
    const unsigned short* __restrict__ W2T2, const unsigned short* __restrict__ W2T3,
    const float* __restrict__ b20, const float* __restrict__ b21,
    const float* __restrict__ b22, const float* __restrict__ b23,
    const int* __restrict__ counts,
    float* __restrict__ out0, float* __restrict__ out1,
    float* __restrict__ out2, float* __restrict__ out3) {
  __shared__ __align__(16) unsigned short Asl[64 * 128];
  __shared__ __align__(16) unsigned short Wsl[64 * 128];
  __shared__ float Ssl[64], Mnl[64];
  int b = blockIdx.x;
  if (b < 512) {
    mgemm_body<5, 1, 0, true>(b, 0, H, W2T0, b20, counts, out0, 320, Asl, Wsl, Ssl, Mnl);
  } else if (b < 768) {
    int l = b - 512;
    mgemm_body<4, 2, 0, false>(l & 127, l >> 7, H + 4194304, W2T1, b21, counts, out1, 640,
                               Asl, Wsl, Ssl, Mnl);
  } else if (b < 896) {
    int l = b - 768;
    mgemm_body<3, 4, 1, false>(l & 31, l >> 5, H + 2 * 4194304, W2T2, b22, counts, out2, 1280,
                               Asl, Wsl, Ssl, Mnl);
  } else {
    int l = b - 896;
    mgemm_body<3, 4, 1, false>(l & 31, l >> 5, H + 3 * 4194304, W2T3, b23, counts, out3, 1280,
                               Asl, Wsl, Ssl, Mnl);
  }
}

// ---------------------------------------------------------------------------
extern "C" void kernel_launch(void* const* d_in, const int* in_sizes, int n_in,
                              void* d_out, int out_size, void* d_ws, size_t ws_size,
                              hipStream_t stream) {
  const float* pe = (const float*)d_in[0];
  const float* kp = (const float*)d_in[1];
  const int* subsets = (const int*)d_in[2];
  const float* w1s = (const float*)d_in[4];
  const float* b1s = (const float*)d_in[5];
  const float* w2l[4] = {(const float*)d_in[6], (const float*)d_in[8],
                         (const float*)d_in[10], (const float*)d_in[12]};
  const float* b2l[4] = {(const float*)d_in[7], (const float*)d_in[9],
                         (const float*)d_in[11], (const float*)d_in[13]};
  float* out = (float*)d_out;

  // workspace layout
  float* part = (float*)d_ws;                        // 4*131072 f32
  int* counts = (int*)(part + 524288);               // 32768
  int* plist = counts + 32768;                       // 32768*32
  unsigned short* H = (unsigned short*)(plist + 1048576);  // 4*4194304 bf16
  unsigned short* W2T0 = H + 16777216;               // 320*128
  unsigned short* W2T1 = W2T0 + 40960;               // 640*128
  unsigned short* W2T2 = W2T1 + 81920;               // 1280*128
  unsigned short* W2T3 = W2T2 + 163840;              // 1280*128

  float* out0 = out;                  // (2,16,320,32,32)
  float* out1 = out + 10485760;       // (2,16,640,16,16)
  float* out2 = out + 15728640;       // (2,16,1280,8,8)
  float* out3 = out + 18350080;       // (2,16,1280,8,8)
  float* lossm = out + 20971520;      // (2,16,4,32,32)

  k_pre<<<dim3(728), dim3(256), 0, stream>>>(w2l[0], w2l[1], w2l[2], w2l[3],
                                             W2T0, W2T1, W2T2, W2T3,
                                             kp, subsets, counts, plist, lossm,
                                             pe, w1s, part);
  k_hid2<<<dim3(4096), dim3(256), 0, stream>>>(part, counts, plist, b1s, H);
  k_mgemm_all<<<dim3(1024), dim3(256), 0, stream>>>(H, W2T0, W2T1, W2T2, W2T3,
                                                    b2l[0], b2l[1], b2l[2], b2l[3],
                                                    counts, out0, out1, out2, out3);
}